// Round 1
// baseline (687.173 us; speedup 1.0000x reference)
//
#include <hip/hip_runtime.h>
#include <math.h>

#define CB 512
#define CS 1024
#define CT 50

__global__ void zero_out_kernel(float* out) { out[0] = 0.0f; }

__global__ __launch_bounds__(64) void crf_scan_kernel(
    const float* __restrict__ scores,    // (B,S,T)
    const int*   __restrict__ tags,      // (B,S)
    const int*   __restrict__ mask,      // (B,S)
    const float* __restrict__ trans,     // (T,T)
    const float* __restrict__ start_tr,  // (T)
    const float* __restrict__ end_tr,    // (T)
    float* __restrict__ out)             // scalar
{
    const int b    = blockIdx.x;
    const int lane = threadIdx.x;

    __shared__ __attribute__((aligned(16))) float sTrans[CT * CT];
    __shared__ __attribute__((aligned(16))) float sP[64];

    // Stage raw transitions in LDS (needed for numerator gathers + E columns).
    for (int k = lane; k < CT * CT; k += 64) sTrans[k] = trans[k];
    __syncthreads();

    // Per-lane E column: ecol[i] = exp(trans[i][lane]).  lanes >= CT get zeros.
    float ecol[CT];
    if (lane < CT) {
        #pragma unroll
        for (int i = 0; i < CT; ++i) ecol[i] = __expf(sTrans[i * CT + lane]);
    } else {
        #pragma unroll
        for (int i = 0; i < CT; ++i) ecol[i] = 0.0f;
    }

    // Sequence length (mask is a prefix mask: sum == length).
    const int* mrow = mask + (size_t)b * CS;
    int len = 0;
    for (int t = lane; t < CS; t += 64) len += mrow[t];
    #pragma unroll
    for (int off = 32; off; off >>= 1) len += __shfl_xor(len, off);

    const float* srow = scores + (size_t)b * CS * CT;

    // alpha_0 = start + emission(t=0)
    float alpha = (lane < CT) ? (start_tr[lane] + srow[lane]) : -INFINITY;

    // ---- forward scan (early exit at len: reference freezes alpha after len) ----
    for (int t = 1; t < len; ++t) {
        float x = (lane < CT) ? srow[(size_t)t * CT + lane] : 0.0f;

        // wave max-reduce of alpha (lanes >= CT hold -inf)
        float m = alpha;
        #pragma unroll
        for (int off = 32; off; off >>= 1) m = fmaxf(m, __shfl_xor(m, off));

        float p = __expf(alpha - m);   // exp(-inf)=0 for pad lanes

        __syncthreads();               // WAR: prior iteration's reads done
        sP[lane] = p;
        __syncthreads();               // RAW: p visible

        // q[lane] = sum_i p[i] * E[i][lane]  (vectorized LDS broadcast reads)
        float q0 = 0.f, q1 = 0.f, q2 = 0.f, q3 = 0.f;
        #pragma unroll
        for (int i = 0; i < 48; i += 4) {
            const float4 pv = *(const float4*)&sP[i];
            q0 = fmaf(pv.x, ecol[i + 0], q0);
            q1 = fmaf(pv.y, ecol[i + 1], q1);
            q2 = fmaf(pv.z, ecol[i + 2], q2);
            q3 = fmaf(pv.w, ecol[i + 3], q3);
        }
        q0 = fmaf(sP[48], ecol[48], q0);
        q1 = fmaf(sP[49], ecol[49], q1);
        float q = (q0 + q1) + (q2 + q3);

        float na = m + __logf(q) + x;
        alpha = (lane < CT) ? na : -INFINITY;
    }

    // ---- denominator: logsumexp(alpha + end) ----
    float v  = (lane < CT) ? (alpha + end_tr[lane]) : -INFINITY;
    float m2 = v;
    #pragma unroll
    for (int off = 32; off; off >>= 1) m2 = fmaxf(m2, __shfl_xor(m2, off));
    float e = (lane < CT) ? __expf(v - m2) : 0.0f;
    float ssum = e;
    #pragma unroll
    for (int off = 32; off; off >>= 1) ssum += __shfl_xor(ssum, off);
    float den = m2 + __logf(ssum);

    // ---- numerator: gold-path score ----
    const int* trow = tags + (size_t)b * CS;
    float nsum = 0.0f;
    for (int t = lane; t < CS; t += 64) {
        if (t < len) {
            int tg = trow[t];
            nsum += srow[(size_t)t * CT + tg];
            if (t >= 1) nsum += sTrans[trow[t - 1] * CT + tg];
        }
    }
    #pragma unroll
    for (int off = 32; off; off >>= 1) nsum += __shfl_xor(nsum, off);

    if (lane == 0) {
        nsum += start_tr[trow[0]] + end_tr[trow[len - 1]];
        // loss = sum_b (den - num) / B
        atomicAdd(out, (den - nsum) * (1.0f / CB));
    }
}

extern "C" void kernel_launch(void* const* d_in, const int* in_sizes, int n_in,
                              void* d_out, int out_size, void* d_ws, size_t ws_size,
                              hipStream_t stream) {
    const float* scores   = (const float*)d_in[0];
    const int*   tags     = (const int*)d_in[1];
    const int*   mask     = (const int*)d_in[2];
    const float* trans    = (const float*)d_in[3];
    const float* start_tr = (const float*)d_in[4];
    const float* end_tr   = (const float*)d_in[5];
    float* out = (float*)d_out;

    zero_out_kernel<<<1, 1, 0, stream>>>(out);
    crf_scan_kernel<<<CB, 64, 0, stream>>>(scores, tags, mask, trans,
                                           start_tr, end_tr, out);
}

// Round 2
// 496.346 us; speedup vs baseline: 1.3845x; 1.3845x over previous
//
#include <hip/hip_runtime.h>
#include <math.h>

#define CB 512
#define CS 1024
#define CT 50
#define PF 4   // x-prefetch depth (register circular buffer)

__global__ void zero_out_kernel(float* out) { out[0] = 0.0f; }

// Compiler-level fence: keeps the MI scheduler and IR passes from reordering
// LDS ops across it. No hardware instruction is emitted (no vmcnt drain!),
// which is the whole point — same-wave DS ops complete in order on CDNA.
__device__ __forceinline__ void wave_fence() {
    __builtin_amdgcn_wave_barrier();
    asm volatile("" ::: "memory");
}

__global__ __launch_bounds__(64) void crf_scan_kernel(
    const float* __restrict__ scores,    // (B,S,T)
    const int*   __restrict__ tags,      // (B,S)
    const int*   __restrict__ mask,      // (B,S)
    const float* __restrict__ trans,     // (T,T)
    const float* __restrict__ start_tr,  // (T)
    const float* __restrict__ end_tr,    // (T)
    float* __restrict__ out)             // scalar
{
    const int b    = blockIdx.x;
    const int lane = threadIdx.x;
    const int xl   = (lane < CT) ? lane : 0;   // clamped lane for safe loads

    __shared__ __attribute__((aligned(16))) float sTrans[CT * CT];
    __shared__ __attribute__((aligned(16))) float sP[64];

    for (int k = lane; k < CT * CT; k += 64) sTrans[k] = trans[k];
    __syncthreads();   // once, outside the scan loop — harmless

    // Per-lane E column: ecol[i] = exp(trans[i][lane]).
    float ecol[CT];
    #pragma unroll
    for (int i = 0; i < CT; ++i) ecol[i] = __expf(sTrans[i * CT + xl]);

    // Sequence length (prefix mask: sum == length).
    const int* mrow = mask + (size_t)b * CS;
    int len = 0;
    for (int t = lane; t < CS; t += 64) len += mrow[t];
    #pragma unroll
    for (int off = 32; off; off >>= 1) len += __shfl_xor(len, off);

    const float* srow = scores + (size_t)b * CS * CT;
    const float* sx   = srow + xl;

    // alpha_0 = start + emission(t=0).  Pad lanes carry harmless garbage:
    // sP is only ever read at indices < CT, and the final reduce masks them.
    float alpha = start_tr[xl] + sx[0];

    // One scan step. Shift by lane-0 alpha (any shift is exact math; spread
    // |alpha_i - alpha_j| <= ~12 keeps exp well inside fp32 range).
    #define STEP(XV)                                                        \
    {                                                                       \
        float m = __int_as_float(                                           \
            __builtin_amdgcn_readlane(__float_as_int(alpha), 0));           \
        float p = __expf(alpha - m);                                        \
        sP[lane] = p;                                                       \
        wave_fence();  /* write visible to in-order same-wave reads */      \
        float q0 = 0.f, q1 = 0.f, q2 = 0.f, q3 = 0.f;                       \
        _Pragma("unroll")                                                   \
        for (int i = 0; i < 48; i += 4) {                                   \
            const float4 pv = *(const float4*)&sP[i];                       \
            q0 = fmaf(pv.x, ecol[i + 0], q0);                               \
            q1 = fmaf(pv.y, ecol[i + 1], q1);                               \
            q2 = fmaf(pv.z, ecol[i + 2], q2);                               \
            q3 = fmaf(pv.w, ecol[i + 3], q3);                               \
        }                                                                   \
        {                                                                   \
            const float2 pv2 = *(const float2*)&sP[48];                     \
            q0 = fmaf(pv2.x, ecol[48], q0);                                 \
            q1 = fmaf(pv2.y, ecol[49], q1);                                 \
        }                                                                   \
        wave_fence();  /* WAR: reads done before next iteration's write */  \
        float q = (q0 + q1) + (q2 + q3);                                    \
        alpha = m + __logf(q) + (XV);                                       \
    }

    // ---- forward scan with 4-deep x prefetch, no barriers ----
    float xpf[PF];
    #pragma unroll
    for (int k = 0; k < PF; ++k) {
        int tt = 1 + k; tt = (tt < len) ? tt : 0;      // clamp: load is safe
        xpf[k] = sx[(size_t)tt * CT];
    }
    int t = 1;
    while (t + PF <= len) {
        float xc[PF];
        #pragma unroll
        for (int k = 0; k < PF; ++k) xc[k] = xpf[k];
        #pragma unroll
        for (int k = 0; k < PF; ++k) {                 // prefetch next chunk
            int tt = t + PF + k; tt = (tt < len) ? tt : 0;
            xpf[k] = sx[(size_t)tt * CT];
        }
        #pragma unroll
        for (int k = 0; k < PF; ++k) STEP(xc[k]);
        t += PF;
    }
    for (int k = 0; t < len; ++t, ++k) STEP(xpf[k]);   // remainder (<PF steps)
    #undef STEP

    // ---- denominator: logsumexp(alpha + end) (exact max-reduce, once) ----
    float v  = (lane < CT) ? (alpha + end_tr[xl]) : -INFINITY;
    float m2 = v;
    #pragma unroll
    for (int off = 32; off; off >>= 1) m2 = fmaxf(m2, __shfl_xor(m2, off));
    float e = (lane < CT) ? __expf(v - m2) : 0.0f;
    float ssum = e;
    #pragma unroll
    for (int off = 32; off; off >>= 1) ssum += __shfl_xor(ssum, off);
    float den = m2 + __logf(ssum);

    // ---- numerator: gold-path score ----
    const int* trow = tags + (size_t)b * CS;
    float nsum = 0.0f;
    for (int tt = lane; tt < CS; tt += 64) {
        if (tt < len) {
            int tg = trow[tt];
            nsum += srow[(size_t)tt * CT + tg];
            if (tt >= 1) nsum += sTrans[trow[tt - 1] * CT + tg];
        }
    }
    #pragma unroll
    for (int off = 32; off; off >>= 1) nsum += __shfl_xor(nsum, off);

    if (lane == 0) {
        nsum += start_tr[trow[0]] + end_tr[trow[len - 1]];
        atomicAdd(out, (den - nsum) * (1.0f / CB));
    }
}

extern "C" void kernel_launch(void* const* d_in, const int* in_sizes, int n_in,
                              void* d_out, int out_size, void* d_ws, size_t ws_size,
                              hipStream_t stream) {
    const float* scores   = (const float*)d_in[0];
    const int*   tags     = (const int*)d_in[1];
    const int*   mask     = (const int*)d_in[2];
    const float* trans    = (const float*)d_in[3];
    const float* start_tr = (const float*)d_in[4];
    const float* end_tr   = (const float*)d_in[5];
    float* out = (float*)d_out;

    zero_out_kernel<<<1, 1, 0, stream>>>(out);
    crf_scan_kernel<<<CB, 64, 0, stream>>>(scores, tags, mask, trans,
                                           start_tr, end_tr, out);
}

// Round 3
// 293.027 us; speedup vs baseline: 2.3451x; 1.6939x over previous
//
#include <hip/hip_runtime.h>
#include <math.h>

#define CB 512
#define CS 1024
#define CT 50
#define PF 4   // x-prefetch depth / renorm cadence

__global__ void zero_out_kernel(float* out) { out[0] = 0.0f; }

// Compiler-level fence only (no hardware waitcnt drain). Same-wave DS ops
// execute in order on CDNA; we just stop the compiler from reordering.
__device__ __forceinline__ void wave_fence() {
    __builtin_amdgcn_wave_barrier();
    asm volatile("" ::: "memory");
}

__device__ __forceinline__ int lane0_bits(float v) {
    return __builtin_amdgcn_readlane(__float_as_int(v), 0);
}

__global__ __launch_bounds__(128) void crf_scan_kernel(
    const float* __restrict__ scores,    // (B,S,T)
    const int*   __restrict__ tags,      // (B,S)
    const int*   __restrict__ mask,      // (B,S)
    const float* __restrict__ trans,     // (T,T)
    const float* __restrict__ start_tr,  // (T)
    const float* __restrict__ end_tr,    // (T)
    float* __restrict__ out)             // scalar
{
    const int b    = blockIdx.x;
    const int tid  = threadIdx.x;
    const int w    = tid >> 6;           // wave 0 = forward, wave 1 = backward
    const int lane = tid & 63;
    const int xl   = (lane < CT) ? lane : 0;

    __shared__ __attribute__((aligned(16))) float sTrans[CT * CT];
    __shared__ __attribute__((aligned(16))) float sP[2][64];
    __shared__ __attribute__((aligned(16))) float sA[64];
    __shared__ __attribute__((aligned(16))) float sB[64];
    __shared__ float sLZ[2], sN[2];

    for (int k = tid; k < CT * CT; k += 128) sTrans[k] = trans[k];
    __syncthreads();

    // wave 0 needs column `lane` of E = exp(trans); wave 1 needs row `lane`.
    float ev[CT];
    #pragma unroll
    for (int i = 0; i < CT; ++i)
        ev[i] = __expf((w == 0) ? sTrans[i * CT + xl] : sTrans[xl * CT + i]);

    // sequence length (prefix mask)
    const int* mrow = mask + (size_t)b * CS;
    int len = 0;
    for (int t = lane; t < CS; t += 64) len += mrow[t];
    #pragma unroll
    for (int off = 32; off; off >>= 1) len += __shfl_xor(len, off);

    const float* srow = scores + (size_t)b * CS * CT;
    const float* sx   = srow + xl;

    const int tm = (len - 1) >> 1;   // split point: fwd -> alpha_tm, bwd -> beta_tm

    // step counts & index walk: idx(k) = base + dir*k
    const int count = (w == 0) ? tm : ((len >= 2) ? (len - 2 - tm) : 0);
    const int base  = (w == 0) ? 1 : (len - 2);
    const int dir   = (w == 0) ? 1 : -1;

    // linear-domain state
    // fwd: a_0 = exp(start + x_0); bwd: C_{len-1} = exp(end + x_{len-1})
    float st = (w == 0) ? __expf(start_tr[xl] + sx[0])
                        : ((len >= 2) ? __expf(end_tr[xl] + sx[(size_t)(len - 1) * CT])
                                      : __expf(end_tr[xl]));
    int   kexp = 0;                  // exact power-of-2 renorm accumulator
    float* myP = sP[w];

    // one scan step: write state, broadcast-dot with ev, scale by prefetched exp(x)
    #define STEP(EXK)                                                       \
    {                                                                       \
        myP[lane] = st;                                                     \
        wave_fence();                                                       \
        float q0 = 0.f, q1 = 0.f, q2 = 0.f, q3 = 0.f;                       \
        _Pragma("unroll")                                                   \
        for (int i = 0; i < 48; i += 4) {                                   \
            const float4 pv = *(const float4*)&myP[i];                      \
            q0 = fmaf(pv.x, ev[i + 0], q0);                                 \
            q1 = fmaf(pv.y, ev[i + 1], q1);                                 \
            q2 = fmaf(pv.z, ev[i + 2], q2);                                 \
            q3 = fmaf(pv.w, ev[i + 3], q3);                                 \
        }                                                                   \
        {                                                                   \
            const float2 pv2 = *(const float2*)&myP[48];                    \
            q0 = fmaf(pv2.x, ev[48], q0);                                   \
            q1 = fmaf(pv2.y, ev[49], q1);                                   \
        }                                                                   \
        wave_fence();                                                       \
        st = ((q0 + q1) + (q2 + q3)) * (EXK);                               \
    }

    // renorm by the power-of-2 part of lane 0: exact division, integer log
    #define RENORM()                                                        \
    {                                                                       \
        int sb = lane0_bits(st);                                            \
        int e  = (sb >> 23) & 0xff;                                         \
        kexp  += e - 127;                                                   \
        st    *= __int_as_float((254 - e) << 23);                           \
    }

    // ---- main scan: 4-step chunks, 4-deep x prefetch, renorm per chunk ----
    float xpf[PF];
    #pragma unroll
    for (int k = 0; k < PF; ++k) {
        int idx = base + dir * k;
        if (idx < 0) idx = 0;
        xpf[k] = sx[(size_t)idx * CT];
    }
    int k = 0;
    while (k + PF <= count) {
        float exk[PF];
        #pragma unroll
        for (int j = 0; j < PF; ++j) exk[j] = __expf(xpf[j]);
        #pragma unroll
        for (int j = 0; j < PF; ++j) {
            int idx = base + dir * (k + PF + j);
            if (idx < 0) idx = 0;
            xpf[j] = sx[(size_t)idx * CT];
        }
        RENORM();
        STEP(exk[0]); STEP(exk[1]); STEP(exk[2]); STEP(exk[3]);
        k += PF;
    }
    for (int r = 0; k < count; ++k, ++r) {
        float exk = __expf(xpf[r]);
        RENORM();
        STEP(exk);
    }

    // bwd epilogue: one plain dot (no exp(x) factor): B_tm = E * C_{tm+1}
    if (w == 1 && len >= 2) { STEP(1.0f) }
    RENORM();
    #undef STEP
    #undef RENORM

    // ---- combine ----
    if (w == 0) sA[lane] = (lane < CT) ? st : 0.0f;
    else        sB[lane] = (lane < CT) ? st : 0.0f;
    if (lane == 0) sLZ[w] = (float)kexp * 0.6931471805599453f;
    __syncthreads();

    // numerator: gold-path score, all 128 threads
    const int* trow = tags + (size_t)b * CS;
    float nsum = 0.0f;
    for (int t = tid; t < CS; t += 128) {
        if (t < len) {
            int tg = trow[t];
            nsum += srow[(size_t)t * CT + tg];
            if (t >= 1) nsum += sTrans[trow[t - 1] * CT + tg];
        }
    }
    #pragma unroll
    for (int off = 32; off; off >>= 1) nsum += __shfl_xor(nsum, off);
    if (lane == 0) sN[w] = nsum;

    float den = 0.0f;
    if (w == 0) {
        float vp = sA[lane] * sB[lane];
        #pragma unroll
        for (int off = 32; off; off >>= 1) vp += __shfl_xor(vp, off);
        den = sLZ[0] + sLZ[1] + __logf(vp);
    }
    __syncthreads();

    if (tid == 0) {
        float num = sN[0] + sN[1] + start_tr[trow[0]] + end_tr[trow[len - 1]];
        atomicAdd(out, (den - num) * (1.0f / CB));
    }
}

extern "C" void kernel_launch(void* const* d_in, const int* in_sizes, int n_in,
                              void* d_out, int out_size, void* d_ws, size_t ws_size,
                              hipStream_t stream) {
    const float* scores   = (const float*)d_in[0];
    const int*   tags     = (const int*)d_in[1];
    const int*   mask     = (const int*)d_in[2];
    const float* trans    = (const float*)d_in[3];
    const float* start_tr = (const float*)d_in[4];
    const float* end_tr   = (const float*)d_in[5];
    float* out = (float*)d_out;

    zero_out_kernel<<<1, 1, 0, stream>>>(out);
    crf_scan_kernel<<<CB, 128, 0, stream>>>(scores, tags, mask, trans,
                                            start_tr, end_tr, out);
}